// Round 1
// baseline (1518.137 us; speedup 1.0000x reference)
//
#include <hip/hip_runtime.h>
#include <stdint.h>
#include <stddef.h>

// ---------- types ----------
typedef __attribute__((ext_vector_type(8))) short bf16x8;
typedef __attribute__((ext_vector_type(4))) float f32x4;
typedef __attribute__((ext_vector_type(8))) _Float16 f16x8;

__device__ __forceinline__ short f2bf(float x) {
  uint32_t u = __builtin_bit_cast(uint32_t, x);
  u += 0x7fffu + ((u >> 16) & 1u);
  return (short)(u >> 16);
}

// ---------- problem constants ----------
// B=16 N=512 H=768 G=8 D=96 L=16 LD=1536
#define PB 16
#define PN 512
#define PH 768
#define PG 8
#define PD 96
#define PL 16
#define PLD 1536

// LDS row strides (shorts) for GEMM tiles: 32+8 -> 80B rows, 16B aligned, 2-way banks
#define LDS_STRIDE 40

// ---------- K0: transpose + convert weights to bf16 ----------
// src: R x C fp32 row-major; dst: C x R bf16 row-major (i.e. src^T)
__global__ void transpose_bf16_k(const float* __restrict__ src, short* __restrict__ dst,
                                 int R, int C) {
  __shared__ float tile[32][33];
  int c0 = blockIdx.x * 32, r0 = blockIdx.y * 32;
  int tx = threadIdx.x;        // 0..31
  int ty = threadIdx.y;        // 0..7
  for (int i = 0; i < 4; i++) {
    int r = r0 + ty + i * 8;
    tile[ty + i * 8][tx] = src[(size_t)r * C + c0 + tx];
  }
  __syncthreads();
  for (int i = 0; i < 4; i++) {
    int c = c0 + ty + i * 8;
    dst[(size_t)c * R + r0 + tx] = f2bf(tile[tx][ty + i * 8]);
  }
}

// ---------- K1: fused QKV GEMM ----------
// C(8192x3072) = X(8192x768 fp32) * Wqkv^T(3072x768 bf16)
// epilogue scatter: q,k -> (b,g,n,d) bf16 ; v(+bv) -> (b,l,d,m) bf16 (transposed)
__global__ __launch_bounds__(256) void gemm_qkv_k(
    const float* __restrict__ X, const short* __restrict__ Wt,
    const float* __restrict__ bv,
    short* __restrict__ qb, short* __restrict__ kb, short* __restrict__ vbt) {
  __shared__ short As[128 * LDS_STRIDE];
  __shared__ short Bs[128 * LDS_STRIDE];
  int n0 = blockIdx.x * 128;
  int m0 = blockIdx.y * 128;
  int tid = threadIdx.x;
  int wave = tid >> 6, lane = tid & 63, quad = lane >> 4, l16 = lane & 15;
  int wm = wave & 1, wn = wave >> 1;

  f32x4 acc[4][4] = {};

  for (int k0 = 0; k0 < PH; k0 += 32) {
    // stage A (fp32 -> bf16): 128x32, 4 chunks of float4 per thread
    for (int t = 0; t < 4; t++) {
      int idx = tid + t * 256;
      int r = idx >> 3, c4 = idx & 7;
      const float4 v = *(const float4*)(X + (size_t)(m0 + r) * PH + k0 + c4 * 4);
      short* d = &As[r * LDS_STRIDE + c4 * 4];
      d[0] = f2bf(v.x); d[1] = f2bf(v.y); d[2] = f2bf(v.z); d[3] = f2bf(v.w);
    }
    // stage B (bf16 16B chunks): 128x32, 2 per thread
    for (int t = 0; t < 2; t++) {
      int idx = tid + t * 256;
      int r = idx >> 2, c8 = idx & 3;
      *(bf16x8*)&Bs[r * LDS_STRIDE + c8 * 8] =
          *(const bf16x8*)(Wt + (size_t)(n0 + r) * PH + k0 + c8 * 8);
    }
    __syncthreads();
    bf16x8 af[4], bfv[4];
    for (int i = 0; i < 4; i++)
      af[i] = *(bf16x8*)&As[(wm * 64 + i * 16 + l16) * LDS_STRIDE + quad * 8];
    for (int j = 0; j < 4; j++)
      bfv[j] = *(bf16x8*)&Bs[(wn * 64 + j * 16 + l16) * LDS_STRIDE + quad * 8];
    for (int i = 0; i < 4; i++)
      for (int j = 0; j < 4; j++)
        acc[i][j] = __builtin_amdgcn_mfma_f32_16x16x32_bf16(af[i], bfv[j], acc[i][j], 0, 0, 0);
    __syncthreads();
  }

  for (int i = 0; i < 4; i++) {
    int rowb = m0 + wm * 64 + i * 16 + quad * 4;
    for (int j = 0; j < 4; j++) {
      int col = n0 + wn * 64 + j * 16 + l16;
      for (int r = 0; r < 4; r++) {
        int rw = rowb + r;
        int b = rw >> 9, n = rw & 511;
        float v = acc[i][j][r];
        if (col < PH) {                       // Q
          int g = col / PD, d = col % PD;
          qb[((size_t)(b * PG + g) * PN + n) * PD + d] = f2bf(v);
        } else if (col < 2 * PH) {            // K
          int c = col - PH; int g = c / PD, d = c % PD;
          kb[((size_t)(b * PG + g) * PN + n) * PD + d] = f2bf(v);
        } else {                              // V (transposed store)
          int c = col - 2 * PH; int l = c / PD, d = c % PD;
          v += bv[c];
          vbt[((size_t)(b * PL + l) * PD + d) * PN + n] = f2bf(v);
        }
      }
    }
  }
}

// ---------- K2: scores (MFMA) + sigma^2*eps + G->L projection + mish + bias -> fp16 logits ----------
// grid: (4 m-quarters, 32 n-tiles of 16, B)
__global__ __launch_bounds__(256) void scores_proj_k(
    const short* __restrict__ qb, const short* __restrict__ kb,
    const float* __restrict__ eps, const float* __restrict__ ebias,
    const float* __restrict__ sigma, const float* __restrict__ p,
    unsigned short* __restrict__ logits) {
  __shared__ float sbuf[PG][16 * 68];   // stride 68 floats
  __shared__ float pL[PG][PL];
  __shared__ float sg2[PG];
  int b = blockIdx.z;
  int n0 = blockIdx.y * 16;
  int mq = blockIdx.x;
  int tid = threadIdx.x;
  int wave = tid >> 6, lane = tid & 63, quad = lane >> 4, l16 = lane & 15;
  if (tid < PG * PL) pL[tid >> 4][tid & 15] = p[tid];
  if (tid < PG) { float s = sigma[tid]; sg2[tid] = s * s; }

  const float scale = 0.03608439182435161f;  // 768^-0.5

  for (int mt = 0; mt < 2; mt++) {
    int m0 = mq * 128 + mt * 64;
    // ---- scores: wave handles groups 2w, 2w+1 ----
    for (int gg = 0; gg < 2; gg++) {
      int g = wave * 2 + gg;
      const short* qg = qb + ((size_t)(b * PG + g) * PN + n0) * PD;
      const short* kg = kb + ((size_t)(b * PG + g) * PN + m0) * PD;
      bf16x8 aq[3];
      for (int ks = 0; ks < 3; ks++)
        aq[ks] = *(const bf16x8*)(qg + l16 * PD + ks * 32 + quad * 8);
      for (int ms = 0; ms < 4; ms++) {
        f32x4 acc = {};
        for (int ks = 0; ks < 3; ks++) {
          bf16x8 bk = *(const bf16x8*)(kg + (ms * 16 + l16) * PD + ks * 32 + quad * 8);
          acc = __builtin_amdgcn_mfma_f32_16x16x32_bf16(aq[ks], bk, acc, 0, 0, 0);
        }
        for (int r = 0; r < 4; r++)
          sbuf[g][(quad * 4 + r) * 68 + ms * 16 + l16] = acc[r];
      }
    }
    __syncthreads();
    // ---- projection + mish + bias, 16x64 positions, 4 per thread ----
    for (int sweep = 0; sweep < 4; sweep++) {
      int n = sweep * 4 + wave;
      int m = tid & 63;
      float sv[PG];
      for (int g = 0; g < PG; g++) {
        float e = eps[((size_t)(b * PG + g) * PN + n0 + n) * PN + m0 + m];
        sv[g] = sbuf[g][n * 68 + m] + sg2[g] * e;
      }
      float bias = ebias[((size_t)b * PN + n0 + n) * PN + m0 + m];
      for (int l = 0; l < PL; l++) {
        float a = 0.f;
        for (int g = 0; g < PG; g++) a += sv[g] * pL[g][l];
        // mish(a) = a * ((1+e^a)^2 - 1)/((1+e^a)^2 + 1)
        float ex = __expf(a);
        float t = 1.f + ex;
        float t2 = t * t;
        float mi = (a > 20.f) ? a : a * (t2 - 1.f) / (t2 + 1.f);
        float lg = mi * scale + bias;
        _Float16 h = (_Float16)lg;
        logits[((size_t)(b * PL + l) * PN + n0 + n) * PN + m0 + m] =
            __builtin_bit_cast(unsigned short, h);
      }
    }
    __syncthreads();
  }
}

// ---------- K3: softmax (no max-sub; logits bounded ~|12|) + PV MFMA ----------
// grid: (16 n-tiles of 32, L, B)
#define PR_STRIDE 520
__global__ __launch_bounds__(256) void softmax_pv_k(
    const unsigned short* __restrict__ logits, const short* __restrict__ vbt,
    short* __restrict__ ob) {
  __shared__ short pr[32 * PR_STRIDE];
  __shared__ float invL[32];
  int nt = blockIdx.x, l = blockIdx.y, b = blockIdx.z;
  int n0 = nt * 32;
  int tid = threadIdx.x;
  int wave = tid >> 6, lane = tid & 63, quad = lane >> 4, l16 = lane & 15;

  const unsigned short* lrow = logits + ((size_t)(b * PL + l) * PN + n0) * PN;
  for (int rr = 0; rr < 8; rr++) {
    int row = wave * 8 + rr;
    f16x8 h = *(const f16x8*)(lrow + (size_t)row * PN + lane * 8);
    float e[8]; float s = 0.f;
    for (int i = 0; i < 8; i++) { e[i] = __expf((float)h[i]); s += e[i]; }
    for (int off = 1; off < 64; off <<= 1) s += __shfl_xor(s, off);
    if (lane == 0) invL[row] = 1.f / s;
    bf16x8 pe;
    for (int i = 0; i < 8; i++) pe[i] = f2bf(e[i]);
    *(bf16x8*)&pr[row * PR_STRIDE + lane * 8] = pe;
  }
  __syncthreads();

  int nsub = wave & 1, dh = wave >> 1;   // dh in 0..1, covers 48 d each
  f32x4 acc[3] = {};
  const short* vb = vbt + (size_t)(b * PL + l) * PD * PN;
  for (int ks = 0; ks < 16; ks++) {
    bf16x8 a = *(bf16x8*)&pr[(nsub * 16 + l16) * PR_STRIDE + ks * 32 + quad * 8];
    for (int jj = 0; jj < 3; jj++) {
      int d = dh * 48 + jj * 16 + l16;
      bf16x8 bv_ = *(const bf16x8*)(vb + (size_t)d * PN + ks * 32 + quad * 8);
      acc[jj] = __builtin_amdgcn_mfma_f32_16x16x32_bf16(a, bv_, acc[jj], 0, 0, 0);
    }
  }
  for (int jj = 0; jj < 3; jj++) {
    for (int r = 0; r < 4; r++) {
      int n = nsub * 16 + quad * 4 + r;
      float o = acc[jj][r] * invL[n];
      int d = dh * 48 + jj * 16 + l16;
      ob[((size_t)b * PN + n0 + n) * PLD + l * PD + d] = f2bf(o);
    }
  }
}

// ---------- K4: output GEMM: out(8192x768 fp32) = ob(8192x1536 bf16) * Wout^T(768x1536 bf16) ----------
__global__ __launch_bounds__(256) void gemm_out_k(
    const short* __restrict__ A, const short* __restrict__ Bt,
    float* __restrict__ out) {
  __shared__ short As[128 * LDS_STRIDE];
  __shared__ short Bs[128 * LDS_STRIDE];
  int n0 = blockIdx.x * 128;
  int m0 = blockIdx.y * 128;
  int tid = threadIdx.x;
  int wave = tid >> 6, lane = tid & 63, quad = lane >> 4, l16 = lane & 15;
  int wm = wave & 1, wn = wave >> 1;
  f32x4 acc[4][4] = {};
  for (int k0 = 0; k0 < PLD; k0 += 32) {
    for (int t = 0; t < 2; t++) {
      int idx = tid + t * 256;
      int r = idx >> 2, c8 = idx & 3;
      *(bf16x8*)&As[r * LDS_STRIDE + c8 * 8] =
          *(const bf16x8*)(A + (size_t)(m0 + r) * PLD + k0 + c8 * 8);
    }
    for (int t = 0; t < 2; t++) {
      int idx = tid + t * 256;
      int r = idx >> 2, c8 = idx & 3;
      *(bf16x8*)&Bs[r * LDS_STRIDE + c8 * 8] =
          *(const bf16x8*)(Bt + (size_t)(n0 + r) * PLD + k0 + c8 * 8);
    }
    __syncthreads();
    bf16x8 af[4], bfv[4];
    for (int i = 0; i < 4; i++)
      af[i] = *(bf16x8*)&As[(wm * 64 + i * 16 + l16) * LDS_STRIDE + quad * 8];
    for (int j = 0; j < 4; j++)
      bfv[j] = *(bf16x8*)&Bs[(wn * 64 + j * 16 + l16) * LDS_STRIDE + quad * 8];
    for (int i = 0; i < 4; i++)
      for (int j = 0; j < 4; j++)
        acc[i][j] = __builtin_amdgcn_mfma_f32_16x16x32_bf16(af[i], bfv[j], acc[i][j], 0, 0, 0);
    __syncthreads();
  }
  for (int i = 0; i < 4; i++) {
    int rowb = m0 + wm * 64 + i * 16 + quad * 4;
    for (int j = 0; j < 4; j++) {
      int col = n0 + wn * 64 + j * 16 + l16;
      for (int r = 0; r < 4; r++)
        out[(size_t)(rowb + r) * PH + col] = acc[i][j][r];
    }
  }
}

// ---------- launcher ----------
extern "C" void kernel_launch(void* const* d_in, const int* in_sizes, int n_in,
                              void* d_out, int out_size, void* d_ws, size_t ws_size,
                              hipStream_t stream) {
  (void)in_sizes; (void)n_in; (void)out_size; (void)ws_size;
  const float* x     = (const float*)d_in[0];
  const float* ebias = (const float*)d_in[1];
  const float* eps   = (const float*)d_in[2];
  const float* Wq    = (const float*)d_in[3];
  const float* Wk    = (const float*)d_in[4];
  const float* Wv    = (const float*)d_in[5];
  const float* bv    = (const float*)d_in[6];
  const float* sigma = (const float*)d_in[7];
  const float* p     = (const float*)d_in[8];
  const float* Wout  = (const float*)d_in[9];
  float* out = (float*)d_out;

  char* ws = (char*)d_ws;
  // byte offsets (all 16B aligned)
  short* wqkv_t = (short*)(ws + 0);                    // 3072x768 bf16  = 4,718,592 B
  short* wout_t = (short*)(ws + 4718592);              // 768x1536 bf16  = 2,359,296 B
  short* qb     = (short*)(ws + 7077888);              // (b,g,n,d) bf16 = 12,582,912 B
  short* kb     = (short*)(ws + 19660800);             // (b,g,n,d) bf16 = 12,582,912 B
  short* vbt    = (short*)(ws + 32243712);             // (b,l,d,m) bf16 = 25,165,824 B
  short* ob     = (short*)(ws + 57409536);             // (b,n,l,d) bf16 = 25,165,824 B
  unsigned short* logits = (unsigned short*)(ws + 82575360); // (b,l,n,m) fp16 = 134,217,728 B
  // total ws used: 216,793,088 B

  dim3 tb(32, 8);
  // Wqkv^T rows: [0,768)=Wq^T, [768,1536)=Wk^T, [1536,3072)=Wv^T
  transpose_bf16_k<<<dim3(24, 24), tb, 0, stream>>>(Wq, wqkv_t, PH, PH);
  transpose_bf16_k<<<dim3(24, 24), tb, 0, stream>>>(Wk, wqkv_t + 768 * 768, PH, PH);
  transpose_bf16_k<<<dim3(48, 24), tb, 0, stream>>>(Wv, wqkv_t + 1536 * 768, PH, PLD);
  transpose_bf16_k<<<dim3(24, 48), tb, 0, stream>>>(Wout, wout_t, PLD, PH);

  gemm_qkv_k<<<dim3(24, 64), 256, 0, stream>>>(x, wqkv_t, bv, qb, kb, vbt);
  scores_proj_k<<<dim3(4, 32, 16), 256, 0, stream>>>(qb, kb, eps, ebias, sigma, p, logits);
  softmax_pv_k<<<dim3(16, 16, 16), 256, 0, stream>>>(logits, vbt, ob);
  gemm_out_k<<<dim3(6, 64), 256, 0, stream>>>(ob, wout_t, out);
}

// Round 2
// 696.825 us; speedup vs baseline: 2.1786x; 2.1786x over previous
//
#include <hip/hip_runtime.h>
#include <stdint.h>
#include <stddef.h>

// ---------- types ----------
typedef __attribute__((ext_vector_type(8))) short bf16x8;
typedef __attribute__((ext_vector_type(4))) short s16x4;
typedef __attribute__((ext_vector_type(4))) float f32x4;
typedef __attribute__((ext_vector_type(8))) _Float16 f16x8;

__device__ __forceinline__ short f2bf(float x) {
  uint32_t u = __builtin_bit_cast(uint32_t, x);
  u += 0x7fffu + ((u >> 16) & 1u);
  return (short)(u >> 16);
}

// ---------- problem constants ----------
// B=16 N=512 H=768 G=8 D=96 L=16 LD=1536
#define PB 16
#define PN 512
#define PH 768
#define PG 8
#define PD 96
#define PL 16
#define PLD 1536
#define PC 3072   // qkv concat cols

// LDS row stride (shorts) for GEMM tiles: 32+8 -> 80B rows, 16B aligned, 2-way banks
#define LDS_STRIDE 40

// ---------- K0a: transpose + convert weights to bf16 ----------
__global__ void transpose_bf16_k(const float* __restrict__ src, short* __restrict__ dst,
                                 int R, int C) {
  __shared__ float tile[32][33];
  int c0 = blockIdx.x * 32, r0 = blockIdx.y * 32;
  int tx = threadIdx.x;        // 0..31
  int ty = threadIdx.y;        // 0..7
  for (int i = 0; i < 4; i++) {
    int r = r0 + ty + i * 8;
    tile[ty + i * 8][tx] = src[(size_t)r * C + c0 + tx];
  }
  __syncthreads();
  for (int i = 0; i < 4; i++) {
    int c = c0 + ty + i * 8;
    dst[(size_t)c * R + r0 + tx] = f2bf(tile[tx][ty + i * 8]);
  }
}

// ---------- K0b: convert X fp32 -> bf16 ----------
__global__ __launch_bounds__(256) void convert_bf16_k(const float* __restrict__ src,
                                                      short* __restrict__ dst) {
  int i = (blockIdx.x * 256 + threadIdx.x) * 4;
  float4 v = *(const float4*)(src + i);
  s16x4 o = { f2bf(v.x), f2bf(v.y), f2bf(v.z), f2bf(v.w) };
  *(s16x4*)(dst + i) = o;
}

// ---------- K1: fused QKV GEMM ----------
// C(8192x3072 bf16) = Xb(8192x768 bf16) * Wqkv^T(3072x768 bf16), +bv on v cols.
// Output stored CONTIGUOUS (lane-contiguous cols) - no scatter.
__global__ __launch_bounds__(256) void gemm_qkv_k(
    const short* __restrict__ Xb, const short* __restrict__ Wt,
    const float* __restrict__ bv, short* __restrict__ Cb) {
  __shared__ short As[128 * LDS_STRIDE];
  __shared__ short Bs[128 * LDS_STRIDE];
  int n0 = blockIdx.x * 128;   // output col tile (0..3071)
  int m0 = blockIdx.y * 128;   // output row tile (0..8191)
  int tid = threadIdx.x;
  int wave = tid >> 6, lane = tid & 63, quad = lane >> 4, l16 = lane & 15;
  int wm = wave & 1, wn = wave >> 1;

  f32x4 acc[4][4] = {};

  for (int k0 = 0; k0 < PH; k0 += 32) {
    for (int t = 0; t < 2; t++) {
      int idx = tid + t * 256;
      int r = idx >> 2, c8 = idx & 3;
      *(bf16x8*)&As[r * LDS_STRIDE + c8 * 8] =
          *(const bf16x8*)(Xb + (size_t)(m0 + r) * PH + k0 + c8 * 8);
    }
    for (int t = 0; t < 2; t++) {
      int idx = tid + t * 256;
      int r = idx >> 2, c8 = idx & 3;
      *(bf16x8*)&Bs[r * LDS_STRIDE + c8 * 8] =
          *(const bf16x8*)(Wt + (size_t)(n0 + r) * PH + k0 + c8 * 8);
    }
    __syncthreads();
    bf16x8 af[4], bfv[4];
    for (int i = 0; i < 4; i++)
      af[i] = *(bf16x8*)&As[(wm * 64 + i * 16 + l16) * LDS_STRIDE + quad * 8];
    for (int j = 0; j < 4; j++)
      bfv[j] = *(bf16x8*)&Bs[(wn * 64 + j * 16 + l16) * LDS_STRIDE + quad * 8];
    for (int i = 0; i < 4; i++)
      for (int j = 0; j < 4; j++)
        acc[i][j] = __builtin_amdgcn_mfma_f32_16x16x32_bf16(af[i], bfv[j], acc[i][j], 0, 0, 0);
    __syncthreads();
  }

  // v-section bias (block-uniform branch: col blocks are 128-wide, sections 768-aligned)
  bool isv = (n0 >= 2 * PH);
  float bvr[4] = {0.f, 0.f, 0.f, 0.f};
  if (isv)
    for (int j = 0; j < 4; j++)
      bvr[j] = bv[n0 + wn * 64 + j * 16 + l16 - 2 * PH];

  for (int i = 0; i < 4; i++) {
    int rowb = m0 + wm * 64 + i * 16 + quad * 4;
    for (int j = 0; j < 4; j++) {
      int col = n0 + wn * 64 + j * 16 + l16;
      for (int r = 0; r < 4; r++)
        Cb[(size_t)(rowb + r) * PC + col] = f2bf(acc[i][j][r] + bvr[j]);
    }
  }
}

// ---------- K2: scores (MFMA) + sigma^2*eps + G->L projection + mish + bias -> fp16 logits ----------
// q,k read in-place from Cb. grid: (4 m-quarters, 32 n-tiles of 16, B)
__global__ __launch_bounds__(256) void scores_proj_k(
    const short* __restrict__ Cb,
    const float* __restrict__ eps, const float* __restrict__ ebias,
    const float* __restrict__ sigma, const float* __restrict__ p,
    unsigned short* __restrict__ logits) {
  __shared__ float sbuf[PG][16 * 68];   // stride 68 floats
  __shared__ float pL[PG][PL];
  __shared__ float sg2[PG];
  int b = blockIdx.z;
  int n0 = blockIdx.y * 16;
  int mq = blockIdx.x;
  int tid = threadIdx.x;
  int wave = tid >> 6, lane = tid & 63, quad = lane >> 4, l16 = lane & 15;
  if (tid < PG * PL) pL[tid >> 4][tid & 15] = p[tid];
  if (tid < PG) { float s = sigma[tid]; sg2[tid] = s * s; }

  const float scale = 0.03608439182435161f;  // 768^-0.5

  for (int mt = 0; mt < 2; mt++) {
    int m0 = mq * 128 + mt * 64;
    for (int gg = 0; gg < 2; gg++) {
      int g = wave * 2 + gg;
      const short* qg = Cb + ((size_t)(b * PN) + n0) * PC + g * PD;
      const short* kg = Cb + ((size_t)(b * PN) + m0) * PC + PH + g * PD;
      bf16x8 aq[3];
      for (int ks = 0; ks < 3; ks++)
        aq[ks] = *(const bf16x8*)(qg + (size_t)l16 * PC + ks * 32 + quad * 8);
      for (int ms = 0; ms < 4; ms++) {
        f32x4 acc = {};
        for (int ks = 0; ks < 3; ks++) {
          bf16x8 bk = *(const bf16x8*)(kg + (size_t)(ms * 16 + l16) * PC + ks * 32 + quad * 8);
          acc = __builtin_amdgcn_mfma_f32_16x16x32_bf16(aq[ks], bk, acc, 0, 0, 0);
        }
        for (int r = 0; r < 4; r++)
          sbuf[g][(quad * 4 + r) * 68 + ms * 16 + l16] = acc[r];
      }
    }
    __syncthreads();
    for (int sweep = 0; sweep < 4; sweep++) {
      int n = sweep * 4 + wave;
      int m = tid & 63;
      float sv[PG];
      for (int g = 0; g < PG; g++) {
        float e = eps[((size_t)(b * PG + g) * PN + n0 + n) * PN + m0 + m];
        sv[g] = sbuf[g][n * 68 + m] + sg2[g] * e;
      }
      float bias = ebias[((size_t)b * PN + n0 + n) * PN + m0 + m];
      for (int l = 0; l < PL; l++) {
        float a = 0.f;
        for (int g = 0; g < PG; g++) a += sv[g] * pL[g][l];
        float ex = __expf(a);
        float t = 1.f + ex;
        float t2 = t * t;
        float mi = (a > 20.f) ? a : a * (t2 - 1.f) / (t2 + 1.f);
        float lg = mi * scale + bias;
        _Float16 h = (_Float16)lg;
        logits[((size_t)(b * PL + l) * PN + n0 + n) * PN + m0 + m] =
            __builtin_bit_cast(unsigned short, h);
      }
    }
    __syncthreads();
  }
}

// ---------- K3: V transpose: Cb v-cols (b,n,l,d) -> vbt (b,l,d,m), coalesced both sides ----------
// grid: (16 n-tiles of 32, 48 ld-tiles of 32, B)
__global__ __launch_bounds__(256) void vtrans_k(const short* __restrict__ Cb,
                                               short* __restrict__ vbt) {
  __shared__ short tile[32][36];
  int b = blockIdx.z;
  int ld0 = blockIdx.y * 32;
  int n0 = blockIdx.x * 32;
  int t = threadIdx.x;
  int r = t >> 3, c = (t & 7) * 4;
  *(uint2*)&tile[r][c] =
      *(const uint2*)(Cb + ((size_t)(b * PN) + n0 + r) * PC + 2 * PH + ld0 + c);
  __syncthreads();
  s16x4 o = { tile[c + 0][r], tile[c + 1][r], tile[c + 2][r], tile[c + 3][r] };
  *(s16x4*)(vbt + ((size_t)(b * PLD) + ld0 + c) * PN + n0 + r) = o;
  // note: the four output shorts above go to DIFFERENT rows; store per element instead
}

// corrected element-wise-write version used below
__global__ __launch_bounds__(256) void vtrans2_k(const short* __restrict__ Cb,
                                                 short* __restrict__ vbt) {
  __shared__ short tile[32][36];
  int b = blockIdx.z;
  int ld0 = blockIdx.y * 32;
  int n0 = blockIdx.x * 32;
  int t = threadIdx.x;
  int r = t >> 3, c = (t & 7) * 4;   // r: n-dim row, c: ld-dim col (4 elems)
  *(uint2*)&tile[r][c] =
      *(const uint2*)(Cb + ((size_t)(b * PN) + n0 + r) * PC + 2 * PH + ld0 + c);
  __syncthreads();
  // write: thread covers output row (ld0+r), cols n0+c..c+3 -> read tile[c..c+3-as-n][r-as-ld]
  s16x4 o = { tile[c + 0][r], tile[c + 1][r], tile[c + 2][r], tile[c + 3][r] };
  // here r indexes ld-dim of OUTPUT, c indexes n-dim of OUTPUT:
  *(s16x4*)(vbt + ((size_t)(b * PLD) + ld0 + r) * PN + n0 + c) = o;
}

// ---------- K4: softmax (no max-sub; logits bounded) + PV MFMA ----------
#define PR_STRIDE 520
__global__ __launch_bounds__(256) void softmax_pv_k(
    const unsigned short* __restrict__ logits, const short* __restrict__ vbt,
    short* __restrict__ ob) {
  __shared__ short pr[32 * PR_STRIDE];
  __shared__ float invL[32];
  int nt = blockIdx.x, l = blockIdx.y, b = blockIdx.z;
  int n0 = nt * 32;
  int tid = threadIdx.x;
  int wave = tid >> 6, lane = tid & 63, quad = lane >> 4, l16 = lane & 15;

  const unsigned short* lrow = logits + ((size_t)(b * PL + l) * PN + n0) * PN;
  for (int rr = 0; rr < 8; rr++) {
    int row = wave * 8 + rr;
    f16x8 h = *(const f16x8*)(lrow + (size_t)row * PN + lane * 8);
    float e[8]; float s = 0.f;
    for (int i = 0; i < 8; i++) { e[i] = __expf((float)h[i]); s += e[i]; }
    for (int off = 1; off < 64; off <<= 1) s += __shfl_xor(s, off);
    if (lane == 0) invL[row] = 1.f / s;
    bf16x8 pe;
    for (int i = 0; i < 8; i++) pe[i] = f2bf(e[i]);
    *(bf16x8*)&pr[row * PR_STRIDE + lane * 8] = pe;
  }
  __syncthreads();

  int nsub = wave & 1, dh = wave >> 1;
  f32x4 acc[3] = {};
  const short* vb = vbt + (size_t)(b * PL + l) * PD * PN;
  for (int ks = 0; ks < 16; ks++) {
    bf16x8 a = *(bf16x8*)&pr[(nsub * 16 + l16) * PR_STRIDE + ks * 32 + quad * 8];
    for (int jj = 0; jj < 3; jj++) {
      int d = dh * 48 + jj * 16 + l16;
      bf16x8 bv_ = *(const bf16x8*)(vb + (size_t)d * PN + ks * 32 + quad * 8);
      acc[jj] = __builtin_amdgcn_mfma_f32_16x16x32_bf16(a, bv_, acc[jj], 0, 0, 0);
    }
  }
  for (int jj = 0; jj < 3; jj++) {
    for (int r = 0; r < 4; r++) {
      int n = nsub * 16 + quad * 4 + r;
      float o = acc[jj][r] * invL[n];
      int d = dh * 48 + jj * 16 + l16;
      ob[((size_t)b * PN + n0 + n) * PLD + l * PD + d] = f2bf(o);
    }
  }
}

// ---------- K5: output GEMM: out(8192x768 fp32) = ob(8192x1536 bf16) * Wout^T(768x1536 bf16) ----------
__global__ __launch_bounds__(256) void gemm_out_k(
    const short* __restrict__ A, const short* __restrict__ Bt,
    float* __restrict__ out) {
  __shared__ short As[128 * LDS_STRIDE];
  __shared__ short Bs[128 * LDS_STRIDE];
  int n0 = blockIdx.x * 128;
  int m0 = blockIdx.y * 128;
  int tid = threadIdx.x;
  int wave = tid >> 6, lane = tid & 63, quad = lane >> 4, l16 = lane & 15;
  int wm = wave & 1, wn = wave >> 1;
  f32x4 acc[4][4] = {};
  for (int k0 = 0; k0 < PLD; k0 += 32) {
    for (int t = 0; t < 2; t++) {
      int idx = tid + t * 256;
      int r = idx >> 2, c8 = idx & 3;
      *(bf16x8*)&As[r * LDS_STRIDE + c8 * 8] =
          *(const bf16x8*)(A + (size_t)(m0 + r) * PLD + k0 + c8 * 8);
    }
    for (int t = 0; t < 2; t++) {
      int idx = tid + t * 256;
      int r = idx >> 2, c8 = idx & 3;
      *(bf16x8*)&Bs[r * LDS_STRIDE + c8 * 8] =
          *(const bf16x8*)(Bt + (size_t)(n0 + r) * PLD + k0 + c8 * 8);
    }
    __syncthreads();
    bf16x8 af[4], bfv[4];
    for (int i = 0; i < 4; i++)
      af[i] = *(bf16x8*)&As[(wm * 64 + i * 16 + l16) * LDS_STRIDE + quad * 8];
    for (int j = 0; j < 4; j++)
      bfv[j] = *(bf16x8*)&Bs[(wn * 64 + j * 16 + l16) * LDS_STRIDE + quad * 8];
    for (int i = 0; i < 4; i++)
      for (int j = 0; j < 4; j++)
        acc[i][j] = __builtin_amdgcn_mfma_f32_16x16x32_bf16(af[i], bfv[j], acc[i][j], 0, 0, 0);
    __syncthreads();
  }
  for (int i = 0; i < 4; i++) {
    int rowb = m0 + wm * 64 + i * 16 + quad * 4;
    for (int j = 0; j < 4; j++) {
      int col = n0 + wn * 64 + j * 16 + l16;
      for (int r = 0; r < 4; r++)
        out[(size_t)(rowb + r) * PH + col] = acc[i][j][r];
    }
  }
}

// ---------- launcher ----------
extern "C" void kernel_launch(void* const* d_in, const int* in_sizes, int n_in,
                              void* d_out, int out_size, void* d_ws, size_t ws_size,
                              hipStream_t stream) {
  (void)in_sizes; (void)n_in; (void)out_size; (void)ws_size;
  const float* x     = (const float*)d_in[0];
  const float* ebias = (const float*)d_in[1];
  const float* eps   = (const float*)d_in[2];
  const float* Wq    = (const float*)d_in[3];
  const float* Wk    = (const float*)d_in[4];
  const float* Wv    = (const float*)d_in[5];
  const float* bv    = (const float*)d_in[6];
  const float* sigma = (const float*)d_in[7];
  const float* p     = (const float*)d_in[8];
  const float* Wout  = (const float*)d_in[9];
  float* out = (float*)d_out;

  char* ws = (char*)d_ws;
  // lifetime-aliased workspace layout (total 212,074,496 B):
  //   [0, 134217728)         : logits fp16 (K2->K4); xb bf16 (12.6MB, K0b->K1) aliases start
  //   [134217728, 184549376) : Cb bf16 50.3MB (K1->K3); ob bf16 25MB (K4->K5) aliases start
  //   [184549376, 209715200) : vbt bf16 25MB (K3->K4); wqkv_t 4.7MB (K0a->K1) aliases start
  //   [209715200, 212074496) : wout_t 2.36MB (K0a->K5)
  unsigned short* logits = (unsigned short*)(ws + 0);
  short* xb     = (short*)(ws + 0);
  short* Cb     = (short*)(ws + 134217728);
  short* ob     = (short*)(ws + 134217728);
  short* vbt    = (short*)(ws + 184549376);
  short* wqkv_t = (short*)(ws + 184549376);
  short* wout_t = (short*)(ws + 209715200);

  dim3 tb(32, 8);
  transpose_bf16_k<<<dim3(24, 24), tb, 0, stream>>>(Wq, wqkv_t, PH, PH);
  transpose_bf16_k<<<dim3(24, 24), tb, 0, stream>>>(Wk, wqkv_t + 768 * 768, PH, PH);
  transpose_bf16_k<<<dim3(48, 24), tb, 0, stream>>>(Wv, wqkv_t + 1536 * 768, PH, PLD);
  transpose_bf16_k<<<dim3(24, 48), tb, 0, stream>>>(Wout, wout_t, PLD, PH);
  convert_bf16_k<<<dim3(6144), 256, 0, stream>>>(x, xb);

  gemm_qkv_k<<<dim3(24, 64), 256, 0, stream>>>(xb, wqkv_t, bv, Cb);
  scores_proj_k<<<dim3(4, 32, 16), 256, 0, stream>>>(Cb, eps, ebias, sigma, p, logits);
  vtrans2_k<<<dim3(16, 48, 16), 256, 0, stream>>>(Cb, vbt);
  softmax_pv_k<<<dim3(16, 16, 16), 256, 0, stream>>>(logits, vbt, ob);
  gemm_out_k<<<dim3(6, 64), 256, 0, stream>>>(ob, wout_t, out);
}

// Round 3
// 536.234 us; speedup vs baseline: 2.8311x; 1.2995x over previous
//
#include <hip/hip_runtime.h>
#include <stdint.h>
#include <stddef.h>

// ---------- types ----------
typedef __attribute__((ext_vector_type(8))) short bf16x8;
typedef __attribute__((ext_vector_type(4))) short s16x4;
typedef __attribute__((ext_vector_type(4))) float f32x4;

__device__ __forceinline__ short f2bf(float x) {
  uint32_t u = __builtin_bit_cast(uint32_t, x);
  u += 0x7fffu + ((u >> 16) & 1u);
  return (short)(u >> 16);
}

// async global->LDS, 16B per lane; LDS dest = wave-uniform base + lane*16
__device__ __forceinline__ void gload16(const short* g, short* l) {
  __builtin_amdgcn_global_load_lds(
      (const __attribute__((address_space(1))) void*)g,
      (__attribute__((address_space(3))) void*)l, 16, 0, 0);
}

// ---------- problem constants ----------
// B=16 N=512 H=768 G=8 D=96 L=16 LD=1536
#define PB 16
#define PN 512
#define PH 768
#define PG 8
#define PD 96
#define PL 16
#define PLD 1536
#define PC 3072   // qkv concat cols

// ---------- K0a: transpose + convert weights to bf16 ----------
__global__ void transpose_bf16_k(const float* __restrict__ src, short* __restrict__ dst,
                                 int R, int C) {
  __shared__ float tile[32][33];
  int c0 = blockIdx.x * 32, r0 = blockIdx.y * 32;
  int tx = threadIdx.x;        // 0..31
  int ty = threadIdx.y;        // 0..7
  for (int i = 0; i < 4; i++) {
    int r = r0 + ty + i * 8;
    tile[ty + i * 8][tx] = src[(size_t)r * C + c0 + tx];
  }
  __syncthreads();
  for (int i = 0; i < 4; i++) {
    int c = c0 + ty + i * 8;
    dst[(size_t)c * R + r0 + tx] = f2bf(tile[tx][ty + i * 8]);
  }
}

// ---------- K0b: convert X fp32 -> bf16 ----------
__global__ __launch_bounds__(256) void convert_bf16_k(const float* __restrict__ src,
                                                      short* __restrict__ dst) {
  int i = (blockIdx.x * 256 + threadIdx.x) * 4;
  float4 v = *(const float4*)(src + i);
  s16x4 o = { f2bf(v.x), f2bf(v.y), f2bf(v.z), f2bf(v.w) };
  *(s16x4*)(dst + i) = o;
}

// ---------- K1: fused QKV GEMM (m97-style: global_load_lds, BK=32 unpadded) ----------
// C(8192x3072 bf16) = Xb(8192x768 bf16) * Wqkv^T(3072x768 bf16), +bv on v cols.
__global__ __launch_bounds__(256) void gemm_qkv_k(
    const short* __restrict__ Xb, const short* __restrict__ Wt,
    const float* __restrict__ bv, short* __restrict__ Cb) {
  __shared__ short As[128 * 32];
  __shared__ short Bs[128 * 32];
  int n0 = blockIdx.x * 128;   // output col tile
  int m0 = blockIdx.y * 128;   // output row tile
  int tid = threadIdx.x;
  int wave = tid >> 6, lane = tid & 63, quad = lane >> 4, l16 = lane & 15;
  int wm = wave & 1, wn = wave >> 1;

  f32x4 acc[4][4] = {};

  for (int k0 = 0; k0 < PH; k0 += 32) {
#pragma unroll
    for (int t = 0; t < 2; t++) {
      int rb = (wave * 2 + t) * 16;
      gload16(Xb + (size_t)(m0 + rb + (lane >> 2)) * PH + k0 + (lane & 3) * 8,
              &As[rb * 32]);
      gload16(Wt + (size_t)(n0 + rb + (lane >> 2)) * PH + k0 + (lane & 3) * 8,
              &Bs[rb * 32]);
    }
    __syncthreads();
    bf16x8 af[4], bfv[4];
#pragma unroll
    for (int i = 0; i < 4; i++)
      af[i] = *(bf16x8*)&As[(wm * 64 + i * 16 + l16) * 32 + quad * 8];
#pragma unroll
    for (int j = 0; j < 4; j++)
      bfv[j] = *(bf16x8*)&Bs[(wn * 64 + j * 16 + l16) * 32 + quad * 8];
#pragma unroll
    for (int i = 0; i < 4; i++)
#pragma unroll
      for (int j = 0; j < 4; j++)
        acc[i][j] = __builtin_amdgcn_mfma_f32_16x16x32_bf16(af[i], bfv[j], acc[i][j], 0, 0, 0);
    __syncthreads();
  }

  bool isv = (n0 >= 2 * PH);
  float bvr[4] = {0.f, 0.f, 0.f, 0.f};
  if (isv)
#pragma unroll
    for (int j = 0; j < 4; j++)
      bvr[j] = bv[n0 + wn * 64 + j * 16 + l16 - 2 * PH];

#pragma unroll
  for (int i = 0; i < 4; i++) {
    int rowb = m0 + wm * 64 + i * 16 + quad * 4;
#pragma unroll
    for (int j = 0; j < 4; j++) {
      int col = n0 + wn * 64 + j * 16 + l16;
#pragma unroll
      for (int r = 0; r < 4; r++)
        Cb[(size_t)(rowb + r) * PC + col] = f2bf(acc[i][j][r] + bvr[j]);
    }
  }
}

// ---------- K2: V transpose: Cb v-cols (b,n,l*d) -> vbt (b,l,d,m) ----------
__global__ __launch_bounds__(256) void vtrans2_k(const short* __restrict__ Cb,
                                                 short* __restrict__ vbt) {
  __shared__ short tile[32][36];
  int b = blockIdx.z;
  int ld0 = blockIdx.y * 32;
  int n0 = blockIdx.x * 32;
  int t = threadIdx.x;
  int r = t >> 3, c = (t & 7) * 4;
  *(uint2*)&tile[r][c] =
      *(const uint2*)(Cb + ((size_t)(b * PN) + n0 + r) * PC + 2 * PH + ld0 + c);
  __syncthreads();
  s16x4 o = { tile[c + 0][r], tile[c + 1][r], tile[c + 2][r], tile[c + 3][r] };
  *(s16x4*)(vbt + ((size_t)(b * PLD) + ld0 + r) * PN + n0 + c) = o;
}

// ---------- K3: FUSED scores + eps + G->L proj + mish + softmax + PV ----------
// grid: (32 n-tiles of 16, B). block = 256 (4 waves).
// Per m-tile of 64:
//   P1: QK^T MFMA per group -> sbuf (fp32, union LDS)
//   P2a: read sv into regs; P2b: proj+mish+exp -> pbuf (bf16, union LDS)
//   P3: PV MFMA (wave w handles l = 4w..4w+3) + row-sum MFMA vs all-ones B
#define SB_STR 68   // sbuf float stride per n-row
#define PB_STR 72   // pbuf short stride per n-row
__global__ __launch_bounds__(256, 2) void fused_attn_k(
    const short* __restrict__ Cb, const float* __restrict__ eps,
    const float* __restrict__ ebias, const float* __restrict__ sigma,
    const float* __restrict__ p, const short* __restrict__ vbt,
    short* __restrict__ ob) {
  __shared__ __align__(16) char ubuf[16 * PB_STR * PL * 2];  // 36864 B union
  __shared__ float pLs[PG][PL];
  __shared__ float sg2s[PG];
  float* sb = (float*)ubuf;   // [PG][16*SB_STR] view = 34816 B
  short* pb = (short*)ubuf;   // [PL][16*PB_STR] view = 36864 B

  int n0 = blockIdx.x * 16;
  int b = blockIdx.y;
  int tid = threadIdx.x;
  int wave = tid >> 6, lane = tid & 63, quad = lane >> 4, l16 = lane & 15;

  if (tid < PG * PL) pLs[tid >> 4][tid & 15] = p[tid];
  if (tid < PG) { float s = sigma[tid]; sg2s[tid] = s * s; }
  __syncthreads();
  float sg2r[PG];
#pragma unroll
  for (int g = 0; g < PG; g++) sg2r[g] = sg2s[g];

  const float scale = 0.03608439182435161f;  // 768^-0.5

  // preload Q fragments for this wave's two groups (rows n0..n0+15)
  bf16x8 aq[2][3];
#pragma unroll
  for (int gg = 0; gg < 2; gg++) {
    int g = wave * 2 + gg;
    const short* qg = Cb + ((size_t)(b * PN) + n0 + l16) * PC + g * PD;
#pragma unroll
    for (int ks = 0; ks < 3; ks++)
      aq[gg][ks] = *(const bf16x8*)(qg + ks * 32 + quad * 8);
  }

  // all-ones B fragment for row-sum MFMA
  bf16x8 onesf;
#pragma unroll
  for (int j = 0; j < 8; j++) onesf[j] = (short)0x3F80;

  f32x4 oacc[4][6] = {};   // [li][d-tile]; l = wave*4 + li
  f32x4 sacc[4] = {};      // row sums, same C-layout rows as oacc

  for (int mt = 0; mt < 8; mt++) {
    int m0 = mt * 64;
    // ---- eps/bias prefetch into regs (consumed in P2) ----
    float er[4][PG];
    float br[4];
#pragma unroll
    for (int s = 0; s < 4; s++) {
      int n = wave + 4 * s;
#pragma unroll
      for (int g = 0; g < PG; g++)
        er[s][g] = eps[((size_t)(b * PG + g) * PN + n0 + n) * PN + m0 + lane];
      br[s] = ebias[((size_t)b * PN + n0 + n) * PN + m0 + lane];
    }
    // ---- P1: scores for this wave's 2 groups (16n x 64m) ----
#pragma unroll
    for (int gg = 0; gg < 2; gg++) {
      int g = wave * 2 + gg;
      const short* kg = Cb + ((size_t)(b * PN) + m0) * PC + PH + g * PD;
#pragma unroll
      for (int ms = 0; ms < 4; ms++) {
        f32x4 acc = {};
#pragma unroll
        for (int ks = 0; ks < 3; ks++) {
          bf16x8 bk = *(const bf16x8*)(kg + (size_t)(ms * 16 + l16) * PC + ks * 32 + quad * 8);
          acc = __builtin_amdgcn_mfma_f32_16x16x32_bf16(aq[gg][ks], bk, acc, 0, 0, 0);
        }
#pragma unroll
        for (int r = 0; r < 4; r++)
          sb[g * (16 * SB_STR) + (quad * 4 + r) * SB_STR + ms * 16 + l16] = acc[r];
      }
    }
    __syncthreads();   // B1: sbuf written -> readable
    // ---- P2a: consume sbuf into registers ----
    float sv[4][PG];
#pragma unroll
    for (int s = 0; s < 4; s++) {
      int n = wave + 4 * s;
#pragma unroll
      for (int g = 0; g < PG; g++)
        sv[s][g] = sb[g * (16 * SB_STR) + n * SB_STR + lane] + sg2r[g] * er[s][g];
    }
    __syncthreads();   // B2: sbuf fully read -> safe to overwrite as pbuf
    // ---- P2b: proj + mish + exp -> pbuf ----
    for (int l = 0; l < PL; l++) {
      float a0 = 0.f, a1 = 0.f, a2 = 0.f, a3 = 0.f;
#pragma unroll
      for (int g = 0; g < PG; g++) {
        float pv = pLs[g][l];
        a0 += sv[0][g] * pv; a1 += sv[1][g] * pv;
        a2 += sv[2][g] * pv; a3 += sv[3][g] * pv;
      }
      float as[4] = {a0, a1, a2, a3};
#pragma unroll
      for (int s = 0; s < 4; s++) {
        float a = as[s];
        float ex = __expf(a);
        float t = 1.f + ex;
        float r2 = t * t;
        float mi = (a > 20.f) ? a : a * (r2 - 1.f) * __builtin_amdgcn_rcpf(r2 + 1.f);
        float e = __expf(mi * scale + br[s]);
        pb[l * (16 * PB_STR) + (wave + 4 * s) * PB_STR + lane] = f2bf(e);
      }
    }
    __syncthreads();   // B3: pbuf written -> readable
    // ---- P3: PV + rowsum MFMA; wave handles l = wave*4 + li ----
#pragma unroll
    for (int li = 0; li < 4; li++) {
      int l = wave * 4 + li;
      bf16x8 af0 = *(bf16x8*)&pb[l * (16 * PB_STR) + l16 * PB_STR + 0 + quad * 8];
      bf16x8 af1 = *(bf16x8*)&pb[l * (16 * PB_STR) + l16 * PB_STR + 32 + quad * 8];
      const short* vb = vbt + ((size_t)(b * PL + l) * PD) * PN + m0;
#pragma unroll
      for (int dt = 0; dt < 6; dt++) {
        bf16x8 b0 = *(const bf16x8*)(vb + (size_t)(dt * 16 + l16) * PN + quad * 8);
        bf16x8 b1 = *(const bf16x8*)(vb + (size_t)(dt * 16 + l16) * PN + 32 + quad * 8);
        oacc[li][dt] = __builtin_amdgcn_mfma_f32_16x16x32_bf16(af0, b0, oacc[li][dt], 0, 0, 0);
        oacc[li][dt] = __builtin_amdgcn_mfma_f32_16x16x32_bf16(af1, b1, oacc[li][dt], 0, 0, 0);
      }
      sacc[li] = __builtin_amdgcn_mfma_f32_16x16x32_bf16(af0, onesf, sacc[li], 0, 0, 0);
      sacc[li] = __builtin_amdgcn_mfma_f32_16x16x32_bf16(af1, onesf, sacc[li], 0, 0, 0);
    }
    __syncthreads();   // B4: pbuf read done -> next iter may overwrite
  }

  // ---- epilogue: normalize rows and store (b, n, l*96+d) bf16 ----
#pragma unroll
  for (int li = 0; li < 4; li++) {
    int l = wave * 4 + li;
#pragma unroll
    for (int r = 0; r < 4; r++) {
      int n = quad * 4 + r;
      float inv = __builtin_amdgcn_rcpf(sacc[li][r]);
#pragma unroll
      for (int dt = 0; dt < 6; dt++) {
        float o = oacc[li][dt][r] * inv;
        ob[((size_t)(b * PN) + n0 + n) * PLD + l * PD + dt * 16 + l16] = f2bf(o);
      }
    }
  }
}

// ---------- K4: output GEMM (m97-style): out(8192x768 fp32) = ob * Wout^T ----------
__global__ __launch_bounds__(256) void gemm_out_k(
    const short* __restrict__ A, const short* __restrict__ Bt,
    float* __restrict__ out) {
  __shared__ short As[128 * 32];
  __shared__ short Bs[128 * 32];
  int n0 = blockIdx.x * 128;
  int m0 = blockIdx.y * 128;
  int tid = threadIdx.x;
  int wave = tid >> 6, lane = tid & 63, quad = lane >> 4, l16 = lane & 15;
  int wm = wave & 1, wn = wave >> 1;
  f32x4 acc[4][4] = {};
  for (int k0 = 0; k0 < PLD; k0 += 32) {
#pragma unroll
    for (int t = 0; t < 2; t++) {
      int rb = (wave * 2 + t) * 16;
      gload16(A + (size_t)(m0 + rb + (lane >> 2)) * PLD + k0 + (lane & 3) * 8,
              &As[rb * 32]);
      gload16(Bt + (size_t)(n0 + rb + (lane >> 2)) * PLD + k0 + (lane & 3) * 8,
              &Bs[rb * 32]);
    }
    __syncthreads();
    bf16x8 af[4], bfv[4];
#pragma unroll
    for (int i = 0; i < 4; i++)
      af[i] = *(bf16x8*)&As[(wm * 64 + i * 16 + l16) * 32 + quad * 8];
#pragma unroll
    for (int j = 0; j < 4; j++)
      bfv[j] = *(bf16x8*)&Bs[(wn * 64 + j * 16 + l16) * 32 + quad * 8];
#pragma unroll
    for (int i = 0; i < 4; i++)
#pragma unroll
      for (int j = 0; j < 4; j++)
        acc[i][j] = __builtin_amdgcn_mfma_f32_16x16x32_bf16(af[i], bfv[j], acc[i][j], 0, 0, 0);
    __syncthreads();
  }
#pragma unroll
  for (int i = 0; i < 4; i++) {
    int rowb = m0 + wm * 64 + i * 16 + quad * 4;
#pragma unroll
    for (int j = 0; j < 4; j++) {
      int col = n0 + wn * 64 + j * 16 + l16;
#pragma unroll
      for (int r = 0; r < 4; r++)
        out[(size_t)(rowb + r) * PH + col] = acc[i][j][r];
    }
  }
}

// ---------- launcher ----------
extern "C" void kernel_launch(void* const* d_in, const int* in_sizes, int n_in,
                              void* d_out, int out_size, void* d_ws, size_t ws_size,
                              hipStream_t stream) {
  (void)in_sizes; (void)n_in; (void)out_size; (void)ws_size;
  const float* x     = (const float*)d_in[0];
  const float* ebias = (const float*)d_in[1];
  const float* eps   = (const float*)d_in[2];
  const float* Wq    = (const float*)d_in[3];
  const float* Wk    = (const float*)d_in[4];
  const float* Wv    = (const float*)d_in[5];
  const float* bv    = (const float*)d_in[6];
  const float* sigma = (const float*)d_in[7];
  const float* p     = (const float*)d_in[8];
  const float* Wout  = (const float*)d_in[9];
  float* out = (float*)d_out;

  char* ws = (char*)d_ws;
  // workspace (no aliasing needed now; total ~120.3 MB):
  short* xb     = (short*)(ws + 0);           // 12,582,912 B
  short* wqkv_t = (short*)(ws + 12582912);    //  4,718,592 B
  short* wout_t = (short*)(ws + 17301504);    //  2,359,296 B
  short* Cb     = (short*)(ws + 19660800);    // 50,331,648 B
  short* vbt    = (short*)(ws + 69992448);    // 25,165,824 B
  short* ob     = (short*)(ws + 95158272);    // 25,165,824 B

  dim3 tb(32, 8);
  transpose_bf16_k<<<dim3(24, 24), tb, 0, stream>>>(Wq, wqkv_t, PH, PH);
  transpose_bf16_k<<<dim3(24, 24), tb, 0, stream>>>(Wk, wqkv_t + 768 * 768, PH, PH);
  transpose_bf16_k<<<dim3(48, 24), tb, 0, stream>>>(Wv, wqkv_t + 1536 * 768, PH, PLD);
  transpose_bf16_k<<<dim3(24, 48), tb, 0, stream>>>(Wout, wout_t, PLD, PH);
  convert_bf16_k<<<dim3(6144), 256, 0, stream>>>(x, xb);

  gemm_qkv_k<<<dim3(24, 64), 256, 0, stream>>>(xb, wqkv_t, bv, Cb);
  vtrans2_k<<<dim3(16, 48, 16), 256, 0, stream>>>(Cb, vbt);
  fused_attn_k<<<dim3(32, 16), 256, 0, stream>>>(Cb, eps, ebias, sigma, p, vbt, ob);
  gemm_out_k<<<dim3(6, 64), 256, 0, stream>>>(ob, wout_t, out);
}